// Round 5
// baseline (256.434 us; speedup 1.0000x reference)
//
#include <hip/hip_runtime.h>

// Cumulative product along last dim of (4096, 32768) fp32.
// ONE WAVE PER ROW — no barriers, no LDS, no block-level phasing.
// Each wave streams its row in 128 chunks of 256 elems (64 lanes x float4,
// 1KB fully-coalesced per vmem instruction) with an 8-deep register ring
// prefetch (statically indexed). Plain (cached) loads/stores — the nt path
// measured slower than the L2-acked path. Per chunk: in-thread scan (3 muls)
// -> 6-step shfl_up wave scan -> serial scalar carry -> coalesced store.

#define COLS   32768
#define TPB    256
#define WPB    (TPB / 64)        // 4 waves (rows) per block
#define CHUNK  256               // elems per chunk: 64 lanes * 4
#define NCHUNK (COLS / CHUNK)    // 128
#define PF     8                 // prefetch depth in chunks (8KB in flight/wave)

typedef float f32x4 __attribute__((ext_vector_type(4)));

__global__ __launch_bounds__(TPB) void cumprod_rows(const float* __restrict__ x,
                                                    float* __restrict__ out) {
    const int lane = threadIdx.x & 63;
    const int wid  = threadIdx.x >> 6;
    const int row  = blockIdx.x * WPB + wid;

    const size_t base = (size_t)row * (size_t)COLS + (size_t)lane * 4;
    const float* px = x + base;
    float*       po = out + base;

    // ---- prime the prefetch ring (static indices only) ----
    f32x4 buf[PF];
    #pragma unroll
    for (int j = 0; j < PF; ++j)
        buf[j] = *reinterpret_cast<const f32x4*>(px + j * CHUNK);

    float carry = 1.0f;

    for (int cc = 0; cc < NCHUNK; cc += PF) {
        #pragma unroll
        for (int j = 0; j < PF; ++j) {
            f32x4 v = buf[j];

            // refill this ring slot from PF chunks ahead (wave-uniform branch)
            const int nc = cc + PF + j;
            if (nc < NCHUNK)
                buf[j] = *reinterpret_cast<const f32x4*>(px + nc * CHUNK);

            // in-thread inclusive scan of the 4 elements
            v[1] *= v[0];
            v[2] *= v[1];
            v[3] *= v[2];

            // wave-wide inclusive scan of per-thread totals (64 lanes)
            float t = v[3];
            #pragma unroll
            for (int off = 1; off < 64; off <<= 1) {
                float u = __shfl_up(t, off);
                if (lane >= off) t *= u;
            }
            // exclusive prefix for this lane
            float ex = __shfl_up(t, 1);
            if (lane == 0) ex = 1.0f;

            const float m = carry * ex;

            // chunk total -> next carry (the only serial dependency)
            carry *= __shfl(t, 63);

            f32x4 o;
            o[0] = v[0] * m;
            o[1] = v[1] * m;
            o[2] = v[2] * m;
            o[3] = v[3] * m;
            *reinterpret_cast<f32x4*>(po + (cc + j) * CHUNK) = o;
        }
    }
}

extern "C" void kernel_launch(void* const* d_in, const int* in_sizes, int n_in,
                              void* d_out, int out_size, void* d_ws, size_t ws_size,
                              hipStream_t stream) {
    const float* x = (const float*)d_in[0];
    float* out = (float*)d_out;
    const int rows = out_size / COLS;          // 4096
    cumprod_rows<<<rows / WPB, TPB, 0, stream>>>(x, out);
}